// Round 7
// baseline (662.993 us; speedup 1.0000x reference)
//
#include <hip/hip_runtime.h>
#include <math.h>

#define NROW  131072
#define DIMC  64
#define KCODE 512
#define RPW   16      // rows per wave
#define NTILE 8       // 8 col-tiles of 64 -> 512 codes
#define NBLK  (NROW / (4 * RPW))   // 4 waves/block, 16 rows/wave -> 2048 blocks

typedef float f32x4 __attribute__((ext_vector_type(4)));

// ---- prep: e2[k] = sum_d e[d][k]^2 (sequential d), eT[k][d] = e[d][k], zero dacc
__global__ void prep_kernel(const float* __restrict__ e, float* __restrict__ e2,
                            float* __restrict__ eT, double* __restrict__ dacc) {
  int k = blockIdx.x * 256 + threadIdx.x;
  if (k == 0) *dacc = 0.0;
  if (k < KCODE) {
    float s = 0.f;
    for (int d = 0; d < DIMC; ++d) {
      float v = e[d * KCODE + k];           // coalesced across k
      s = __fadd_rn(s, __fmul_rn(v, v));    // same chain as reference (ef*ef).sum(0)
      eT[k * DIMC + d] = v;                 // transposed codebook for epilogue gather
    }
    e2[k] = s;
  }
}

// ---- ss[row] = sum_d x[row][d]^2, sequential d ascending
__global__ void ss_kernel(const float* __restrict__ x, float* __restrict__ ss) {
  int row = blockIdx.x * 256 + threadIdx.x;
  const float* xr = x + (long)row * DIMC;
  float s = 0.f;
#pragma unroll
  for (int d0 = 0; d0 < DIMC; d0 += 4) {
    f32x4 v = *(const f32x4*)(xr + d0);
    s = __fadd_rn(s, __fmul_rn(v[0], v[0]));
    s = __fadd_rn(s, __fmul_rn(v[1], v[1]));
    s = __fadd_rn(s, __fmul_rn(v[2], v[2]));
    s = __fadd_rn(s, __fmul_rn(v[3], v[3]));
  }
  ss[row] = s;
}

// ---- main: LDS-free. lane = col within 64-wide tile; 16 rows in accumulators.
// A (x) is wave-uniform -> scalar loads; B (e) is per-lane coalesced vector load.
__global__ void __launch_bounds__(256)
quant_kernel(const float* __restrict__ x, const float* __restrict__ e,
             const float* __restrict__ e2, const float* __restrict__ eT,
             const float* __restrict__ ss, float* __restrict__ out,
             float* __restrict__ oidx, double* __restrict__ dacc) {
  const int lane = threadIdx.x & 63;
  const int wid  = blockIdx.x * 4 + (threadIdx.x >> 6);  // 8192 waves total
  const long r0  = (long)wid * RPW;

  // per-row ||x||^2 (wave-uniform values)
  float ssr[RPW];
#pragma unroll
  for (int r = 0; r < RPW; ++r) ssr[r] = ss[r0 + r];

  float minv[RPW];
  int   mini[RPW];
#pragma unroll
  for (int r = 0; r < RPW; ++r) { minv[r] = INFINITY; mini[r] = 0; }

  for (int T = 0; T < NTILE; ++T) {
    const int col = T * 64 + lane;
    const float e2v = e2[col];
    const float* ecol = e + col;

    float acc[RPW];
#pragma unroll
    for (int r = 0; r < RPW; ++r) acc[r] = 0.f;

    for (int d0 = 0; d0 < DIMC; d0 += 4) {
      // B: 4 coalesced per-lane loads (stride 2KB over d), L1/L2-resident
      float b0 = ecol[(d0 + 0) * KCODE];
      float b1 = ecol[(d0 + 1) * KCODE];
      float b2 = ecol[(d0 + 2) * KCODE];
      float b3 = ecol[(d0 + 3) * KCODE];
#pragma unroll
      for (int r = 0; r < RPW; ++r) {
        // A: wave-uniform 16B load -> scalar cache
        f32x4 av = *(const f32x4*)(x + (r0 + r) * DIMC + d0);
        acc[r] = fmaf(av[0], b0, acc[r]);   // d-ascending fmaf chain, matches ref GEMM
        acc[r] = fmaf(av[1], b1, acc[r]);
        acc[r] = fmaf(av[2], b2, acc[r]);
        acc[r] = fmaf(av[3], b3, acc[r]);
      }
    }

#pragma unroll
    for (int r = 0; r < RPW; ++r) {
      float dist = __fadd_rn(__fsub_rn(ssr[r], __fmul_rn(2.0f, acc[r])), e2v);
      if (dist < minv[r]) { minv[r] = dist; mini[r] = col; }  // cols visited ascending
    }
  }

  // cross-lane argmin per row (tie -> lowest col, matching argmin-first semantics)
#pragma unroll
  for (int off = 1; off < 64; off <<= 1) {
#pragma unroll
    for (int r = 0; r < RPW; ++r) {
      float ov = __shfl_xor(minv[r], off, 64);
      int   oi = __shfl_xor(mini[r], off, 64);
      if (ov < minv[r] || (ov == minv[r] && oi < mini[r])) {
        minv[r] = ov; mini[r] = oi;
      }
    }
  }

  // epilogue: out = x + (q - x), idx, diff partial (all lanes hold final mini[r])
  double dsum = 0.0;
#pragma unroll
  for (int r = 0; r < RPW; ++r) {
    const long row = r0 + r;
    const int  idx = mini[r];
    float xv = x[row * DIMC + lane];                // coalesced re-read (L2/L3 warm)
    float q  = eT[(long)idx * DIMC + lane];         // coalesced gather via transposed codebook
    out[row * DIMC + lane] = __fadd_rn(xv, __fsub_rn(q, xv));
    float dq = __fsub_rn(q, xv);
    dsum += (double)__fmul_rn(dq, dq);
    if (lane == 0) oidx[row] = (float)idx;
  }
#pragma unroll
  for (int off = 32; off > 0; off >>= 1)
    dsum += __shfl_down(dsum, off, 64);
  if (lane == 0) atomicAdd(dacc, dsum);
}

// ---- finalize diff + (constant) perplexity
__global__ void fin_kernel(const double* __restrict__ dacc,
                           float* __restrict__ diff_out,
                           float* __restrict__ perp_out) {
  double s = *dacc;
  *diff_out = (float)(s / 8388608.0);
  float p = 1.0f / 512.0f;          // mean(one_hot) == 1/K exactly (reference quirk)
  float lp = logf(p + 1e-10f);
  *perp_out = expf(-(p * lp));
}

extern "C" void kernel_launch(void* const* d_in, const int* in_sizes, int n_in,
                              void* d_out, int out_size, void* d_ws, size_t ws_size,
                              hipStream_t stream) {
  const float* x = (const float*)d_in[0];   // [32,64,64,64]
  const float* e = (const float*)d_in[1];   // [1,1,64,512]
  float* out  = (float*)d_out;              // out | diff | idx | perp
  float* diff = out + 8388608;
  float* oidx = out + 8388609;
  float* perp = out + 8388609 + 131072;

  float*  e2   = (float*)d_ws;                          // 512 f   @ 0
  double* dacc = (double*)((char*)d_ws + 2048);         // 8 B     @ 2048
  float*  eT   = (float*)((char*)d_ws + 4096);          // 128 KiB @ 4096
  float*  ss   = (float*)((char*)d_ws + 4096 + 131072); // 512 KiB

  prep_kernel<<<2, 256, 0, stream>>>(e, e2, eT, dacc);
  ss_kernel<<<NROW / 256, 256, 0, stream>>>(x, ss);
  // NBLK = 2048 blocks x 4 waves x 16 rows = 131072 rows (R2 bug: had /64 here)
  quant_kernel<<<NBLK, 256, 0, stream>>>(x, e, e2, eT, ss, out, oidx, dacc);
  fin_kernel<<<1, 1, 0, stream>>>(dacc, diff, perp);
}